// Round 4
// baseline (123.160 us; speedup 1.0000x reference)
//
#include <hip/hip_runtime.h>
#include <hip/hip_bf16.h>

typedef __attribute__((ext_vector_type(8))) short bf16x8;
typedef __attribute__((ext_vector_type(4))) float f32x4;
typedef __attribute__((ext_vector_type(4))) unsigned short u16x4;
typedef __attribute__((ext_vector_type(8))) unsigned short u16x8;

// ws layout (ushort units):
//   Qb [4][4096][8]  @ 0        bf16, pre-scaled by 0.125, [n][c] fragment layout
//   Kb [4][4096][8]  @ 131072   bf16, [m][c]
//   Vb [4][64][4096] @ 262144   bf16, [v][n]
//   avg floats [4][64] @ ushort offset 1310720 (zeroed via memsetAsync)
#define WS_QB 0
#define WS_KB 131072
#define WS_VB 262144
#define WS_AVG_U 1310720

__device__ __forceinline__ unsigned short bf_hi(float x) {
    __hip_bfloat16 h = __float2bfloat16(x);
    return *reinterpret_cast<unsigned short*>(&h);
}

// ---------------------------------------------------------------------------
// Kernel A: fused QKV projection (MFMA) + channel means (fp32).
// grid = 256 (b = bid>>6, n-tile of 64), 256 threads / 4 waves.
// Per wave: 16 n-columns. B-frag = x columns read direct from global (lane=n,
// k=c, 64B-coalesced). A-frag = W rows from LDS (bf16, [80][72] padded).
// D tiles: tile0 rows = Q(8)+K(8) -> [n][8] fragment layout; tiles1-4 = V.
// ---------------------------------------------------------------------------
__global__ __launch_bounds__(256) void proj_kernel(
    const float* __restrict__ x,
    const float* __restrict__ Wq, const float* __restrict__ bq,
    const float* __restrict__ Wk, const float* __restrict__ bk,
    const float* __restrict__ Wv, const float* __restrict__ bv,
    unsigned short* __restrict__ Qb, unsigned short* __restrict__ Kb,
    unsigned short* __restrict__ Vb, float* __restrict__ avg)
{
    __shared__ __align__(16) unsigned short Wls[80 * 72];

    const int t = threadIdx.x;
    const int w = t >> 6;
    const int l = t & 63;
    const int g = l >> 4;
    const int l15 = l & 15;
    const int b = blockIdx.x >> 6;
    const int n0 = (blockIdx.x & 63) << 6;
    const int n = n0 + w * 16 + l15;
    const float* xb = x + b * 262144;

    // issue x loads early (16 fp32, coalesced 64B segments per inst)
    float xr[2][8];
#pragma unroll
    for (int kcb = 0; kcb < 2; ++kcb)
#pragma unroll
        for (int j = 0; j < 8; ++j)
            xr[kcb][j] = xb[(kcb * 32 + g * 8 + j) * 4096 + n];

    // stage W -> LDS bf16 (rows 0-7 Wq, 8-15 Wk, 16-79 Wv)
#pragma unroll
    for (int i = 0; i < 20; ++i) {
        const int idx = i * 256 + t;
        const int row = idx >> 6, col = idx & 63;
        float wv;
        if (row < 8)       wv = Wq[row * 64 + col];
        else if (row < 16) wv = Wk[(row - 8) * 64 + col];
        else               wv = Wv[(row - 16) * 64 + col];
        Wls[row * 72 + col] = bf_hi(wv);
    }
    __syncthreads();

    bf16x8 bfr[2];
#pragma unroll
    for (int kcb = 0; kcb < 2; ++kcb)
#pragma unroll
        for (int j = 0; j < 8; ++j)
            bfr[kcb][j] = (short)bf_hi(xr[kcb][j]);

#pragma unroll
    for (int tile = 0; tile < 5; ++tile) {
        const bf16x8 a0 = *(const bf16x8*)&Wls[(tile * 16 + l15) * 72 + g * 8];
        const bf16x8 a1 = *(const bf16x8*)&Wls[(tile * 16 + l15) * 72 + 32 + g * 8];
        f32x4 acc;
#pragma unroll
        for (int r = 0; r < 4; ++r) acc[r] = 0.0f;
        acc = __builtin_amdgcn_mfma_f32_16x16x32_bf16(a0, bfr[0], acc, 0, 0, 0);
        acc = __builtin_amdgcn_mfma_f32_16x16x32_bf16(a1, bfr[1], acc, 0, 0, 0);

        if (tile == 0) {
            u16x4 ov;
            if (g < 2) {
#pragma unroll
                for (int r = 0; r < 4; ++r) ov[r] = bf_hi((acc[r] + bq[g * 4 + r]) * 0.125f);
                *(u16x4*)&Qb[(b * 4096 + n) * 8 + g * 4] = ov;
            } else {
#pragma unroll
                for (int r = 0; r < 4; ++r) ov[r] = bf_hi(acc[r] + bk[(g - 2) * 4 + r]);
                *(u16x4*)&Kb[(b * 4096 + n) * 8 + (g - 2) * 4] = ov;
            }
        } else {
#pragma unroll
            for (int r = 0; r < 4; ++r) {
                const int v = (tile - 1) * 16 + g * 4 + r;
                Vb[(b * 64 + v) * 4096 + n] = bf_hi(acc[r] + bv[v]);
            }
        }
    }

    // fused avg: re-read own tile (L2-hot), per-c partial sums, 1 atomic / 4 lanes
    {
        const int c = t >> 2;
        const float* xrow = xb + c * 4096 + n0 + ((t & 3) << 4);
        float s = 0.0f;
#pragma unroll
        for (int k = 0; k < 4; ++k) {
            const float4 v = *(const float4*)&xrow[k * 4];
            s += (v.x + v.y) + (v.z + v.w);
        }
        s += __shfl_xor(s, 1);
        s += __shfl_xor(s, 2);
        if ((t & 3) == 0) atomicAdd(&avg[b * 64 + c], s * (1.0f / 4096.0f));
    }
}

// ---------------------------------------------------------------------------
// Kernel B: attention + gate. grid = 512 (XCD-chunk-swizzled), 256 thr / 4 waves.
// Block = (b, 32-query tile); 2 blocks/CU. Per 64-m tile (2 barriers):
//   phase1: QK^T (1 MFMA/qt, k-groups 1-3 zero) -> exp -> P bf16 LDS (swizzled)
//   phase2: PV via 4 MFMA. V double-buffered, K/V global prefetch, T2 swizzle.
// ---------------------------------------------------------------------------
__global__ __launch_bounds__(256) void attn_kernel(
    const unsigned short* __restrict__ Qb, const unsigned short* __restrict__ Kb,
    const unsigned short* __restrict__ Vb, const float* __restrict__ avg,
    const float* __restrict__ W1, const float* __restrict__ b1,
    const float* __restrict__ W2, const float* __restrict__ b2,
    float* __restrict__ out)
{
    __shared__ __align__(16) unsigned short Vs[2][64][64];
    __shared__ __align__(16) unsigned short Ps[32][64];
    __shared__ float zls[32], gls[64], avgs[64];

    const int t = threadIdx.x;
    const int w = t >> 6;
    const int l = t & 63;
    const int g = l >> 4;
    const int l15 = l & 15;

    // bijective XCD chunk swizzle (512 % 8 == 0): each XCD gets 64 consecutive wgs
    const int wg = (blockIdx.x & 7) * 64 + (blockIdx.x >> 3);
    const int b = wg >> 7;
    const int q0 = (wg & 127) << 5;

    if (t < 32) zls[t] = 0.0f;
    if (t < 64) avgs[t] = avg[b * 64 + t];

    // Q fragments (B operand): col=q, k-group 0 = 8 channels, groups 1-3 zero
    bf16x8 zf = {};
    bf16x8 qf[2];
#pragma unroll
    for (int qt = 0; qt < 2; ++qt) {
        bf16x8 v = *(const bf16x8*)&Qb[(b * 4096 + q0 + qt * 16 + l15) * 8];
        qf[qt] = (g == 0) ? v : zf;
    }

    // V staging geometry: 256 threads stage 64x64 bf16; XOR-swizzled rows
    const int srow = t >> 2;
    const int scol = (t & 3) << 4;
    const int ssw = (srow & 7) << 3;
    const unsigned short* vsrc = &Vb[(b * 64 + srow) * 4096];

    // prologue: stage V tile 0 into buf 0
    {
        u16x8 a = *(const u16x8*)&vsrc[scol];
        u16x8 c = *(const u16x8*)&vsrc[scol + 8];
        *(u16x8*)&Vs[0][srow][scol ^ ssw] = a;
        *(u16x8*)&Vs[0][srow][(scol + 8) ^ ssw] = c;
    }
    // K fragment prefetch (A operand rows = m-stripe of this wave)
    const int mrow = w * 16 + l15;
    bf16x8 kf_next;
    {
        bf16x8 kv = *(const bf16x8*)&Kb[(b * 4096 + mrow) * 8];
        kf_next = (g == 0) ? kv : zf;
    }

    f32x4 acc[2];
#pragma unroll
    for (int qt = 0; qt < 2; ++qt)
#pragma unroll
        for (int r = 0; r < 4; ++r) acc[qt][r] = 0.0f;
    float zreg[2] = {0.f, 0.f};
    const int vsw = (l15 & 7) << 3;   // phase-2 row swizzles (w*16 keeps &7)
    const int psw = (l15 & 7) << 3;

    for (int i = 0; i < 64; ++i) {
        __syncthreads();   // bar A: prev phase2 done with Ps / Vs[(i+1)&1]

        const int inx = (i < 63) ? i + 1 : 63;
        // issue V_{i+1} global loads (consumed after bar B)
        u16x8 va = *(const u16x8*)&vsrc[inx * 64 + scol];
        u16x8 vb2 = *(const u16x8*)&vsrc[inx * 64 + scol + 8];

        // phase 1: scores via MFMA -> exp -> P
        bf16x8 kf = kf_next;
        {
            bf16x8 kv = *(const bf16x8*)&Kb[(b * 4096 + inx * 64 + mrow) * 8];
            kf_next = (g == 0) ? kv : zf;
        }
        f32x4 dz;
#pragma unroll
        for (int r = 0; r < 4; ++r) dz[r] = 0.0f;
#pragma unroll
        for (int qt = 0; qt < 2; ++qt) {
            f32x4 d = __builtin_amdgcn_mfma_f32_16x16x32_bf16(kf, qf[qt], dz, 0, 0, 0);
            float p[4];
#pragma unroll
            for (int r = 0; r < 4; ++r) p[r] = __expf(d[r]);
            zreg[qt] += (p[0] + p[1]) + (p[2] + p[3]);
            u16x4 pw;
#pragma unroll
            for (int r = 0; r < 4; ++r) pw[r] = bf_hi(p[r]);
            const int q = qt * 16 + l15;   // P row; thread's 4 m are contiguous
            *(u16x4*)&Ps[q][(w * 16 + g * 4) ^ ((q & 7) << 3)] = pw;
        }

        __syncthreads();   // bar B: Ps + staged V_i visible

        // stage V_{i+1} -> buf (i+1)&1
        {
            unsigned short* dst = &Vs[(i + 1) & 1][srow][0];
            *(u16x8*)&dst[scol ^ ssw] = va;
            *(u16x8*)&dst[(scol + 8) ^ ssw] = vb2;
        }

        // phase 2: PV MFMAs from Vs[i&1], Ps
        {
            const unsigned short* vbuf = &Vs[i & 1][w * 16 + l15][0];
#pragma unroll
            for (int kcb = 0; kcb < 2; ++kcb) {
                const int colA = kcb * 32 + g * 8;
                const bf16x8 af = *(const bf16x8*)&vbuf[colA ^ vsw];
#pragma unroll
                for (int qt = 0; qt < 2; ++qt) {
                    const bf16x8 bfr = *(const bf16x8*)&Ps[qt * 16 + l15][colA ^ psw];
                    acc[qt] = __builtin_amdgcn_mfma_f32_16x16x32_bf16(af, bfr, acc[qt], 0, 0, 0);
                }
            }
        }
    }

    // z reduction: sum over g-groups (shfl), then over waves (LDS atomic)
#pragma unroll
    for (int qt = 0; qt < 2; ++qt) {
        float z = zreg[qt];
        z += __shfl_xor(z, 16);
        z += __shfl_xor(z, 32);
        if (g == 0) atomicAdd(&zls[qt * 16 + l15], z);
    }
    // SE gate (redundant per block, tiny)
    if (t < 64) {
        float hreg[4];
#pragma unroll
        for (int j = 0; j < 4; ++j) {
            float hh = b1[j];
            for (int c = 0; c < 64; ++c) hh += W1[j * 64 + c] * avgs[c];
            hreg[j] = fmaxf(hh, 0.0f);
        }
        float gg = b2[t];
#pragma unroll
        for (int j = 0; j < 4; ++j) gg += W2[t * 4 + j] * hreg[j];
        gls[t] = 1.0f / (1.0f + __expf(-gg));
    }
    __syncthreads();

#pragma unroll
    for (int qt = 0; qt < 2; ++qt) {
        const int q = qt * 16 + l15;
        const float rz = 1.0f / zls[q];
#pragma unroll
        for (int r = 0; r < 4; ++r) {
            const int v = w * 16 + g * 4 + r;
            out[(b * 64 + v) * 4096 + q0 + q] = acc[qt][r] * rz * gls[v];
        }
    }
}

extern "C" void kernel_launch(void* const* d_in, const int* in_sizes, int n_in,
                              void* d_out, int out_size, void* d_ws, size_t ws_size,
                              hipStream_t stream) {
    const float* x  = (const float*)d_in[0];
    const float* Wq = (const float*)d_in[1];
    const float* bq = (const float*)d_in[2];
    const float* Wk = (const float*)d_in[3];
    const float* bk = (const float*)d_in[4];
    const float* Wv = (const float*)d_in[5];
    const float* bv = (const float*)d_in[6];
    const float* W1 = (const float*)d_in[7];
    const float* b1 = (const float*)d_in[8];
    const float* W2 = (const float*)d_in[9];
    const float* b2 = (const float*)d_in[10];

    unsigned short* wsu = (unsigned short*)d_ws;
    unsigned short* Qb = wsu + WS_QB;
    unsigned short* Kb = wsu + WS_KB;
    unsigned short* Vb = wsu + WS_VB;
    float* avg = (float*)(wsu + WS_AVG_U);
    float* out = (float*)d_out;

    hipMemsetAsync(avg, 0, 256 * sizeof(float), stream);
    proj_kernel<<<256, 256, 0, stream>>>(x, Wq, bq, Wk, bk, Wv, bv, Qb, Kb, Vb, avg);
    attn_kernel<<<512, 256, 0, stream>>>(Qb, Kb, Vb, avg, W1, b1, W2, b2, out);
}

// Round 5
// 114.194 us; speedup vs baseline: 1.0785x; 1.0785x over previous
//
#include <hip/hip_runtime.h>
#include <hip/hip_bf16.h>

typedef __attribute__((ext_vector_type(8))) short bf16x8;
typedef __attribute__((ext_vector_type(4))) float f32x4;
typedef __attribute__((ext_vector_type(4))) unsigned short u16x4;
typedef __attribute__((ext_vector_type(8))) unsigned short u16x8;

// ws layout (ushort units):
//   Qb [4][4096][8]  @ 0        bf16, pre-scaled by 0.125, [n][c] fragment layout
//   Kb [4][4096][8]  @ 131072   bf16, [m][c]
//   Vb [4][64][4096] @ 262144   bf16, [v][n]
//   avg floats [4][64] @ ushort offset 1310720 (zeroed via memsetAsync)
#define WS_QB 0
#define WS_KB 131072
#define WS_VB 262144
#define WS_AVG_U 1310720

__device__ __forceinline__ unsigned short bf_hi(float x) {
    __hip_bfloat16 h = __float2bfloat16(x);
    return *reinterpret_cast<unsigned short*>(&h);
}

// ---------------------------------------------------------------------------
// Kernel A: QKV projection (MFMA) + channel means. grid = 1280 x 256.
// bid: tile = bid>>8 (0..4), pair = bid&255: b = pair>>6, n64 = pair&63.
// tile 0 -> Q(rows 0-7)+K(rows 8-15); tiles 1-4 -> V rows (tile-1)*16..+15.
// Per wave: 16 n-columns, B-frag = x cols direct from global, A-frag = W LDS.
// 5 blocks/CU x 4 waves = 20 waves/CU (R4 had 4: latency-starved).
// ---------------------------------------------------------------------------
__global__ __launch_bounds__(256) void proj_kernel(
    const float* __restrict__ x,
    const float* __restrict__ Wq, const float* __restrict__ bq,
    const float* __restrict__ Wk, const float* __restrict__ bk,
    const float* __restrict__ Wv, const float* __restrict__ bv,
    unsigned short* __restrict__ Qb, unsigned short* __restrict__ Kb,
    unsigned short* __restrict__ Vb, float* __restrict__ avg)
{
    __shared__ __align__(16) unsigned short Wls[16 * 72];

    const int tid = threadIdx.x;
    const int w = tid >> 6;
    const int l = tid & 63;
    const int g = l >> 4;
    const int l15 = l & 15;

    const int tile = blockIdx.x >> 8;
    const int pair = blockIdx.x & 255;
    const int b = pair >> 6;
    const int n0 = (pair & 63) << 6;
    const int n = n0 + w * 16 + l15;
    const float* xb = x + b * 262144;

    // issue x loads early (16 fp32, coalesced)
    float xr[2][8];
#pragma unroll
    for (int kcb = 0; kcb < 2; ++kcb)
#pragma unroll
        for (int j = 0; j < 8; ++j)
            xr[kcb][j] = xb[(kcb * 32 + g * 8 + j) * 4096 + n];

    // stage this tile's 16 W rows -> LDS bf16
#pragma unroll
    for (int i = 0; i < 4; ++i) {
        const int idx = i * 256 + tid;
        const int row = idx >> 6, col = idx & 63;
        float wv;
        if (tile == 0) wv = (row < 8) ? Wq[row * 64 + col] : Wk[(row - 8) * 64 + col];
        else           wv = Wv[((tile - 1) * 16 + row) * 64 + col];
        Wls[row * 72 + col] = bf_hi(wv);
    }
    __syncthreads();

    bf16x8 bfr[2];
#pragma unroll
    for (int kcb = 0; kcb < 2; ++kcb)
#pragma unroll
        for (int j = 0; j < 8; ++j)
            bfr[kcb][j] = (short)bf_hi(xr[kcb][j]);

    const bf16x8 a0 = *(const bf16x8*)&Wls[l15 * 72 + g * 8];
    const bf16x8 a1 = *(const bf16x8*)&Wls[l15 * 72 + 32 + g * 8];
    f32x4 acc;
#pragma unroll
    for (int r = 0; r < 4; ++r) acc[r] = 0.0f;
    acc = __builtin_amdgcn_mfma_f32_16x16x32_bf16(a0, bfr[0], acc, 0, 0, 0);
    acc = __builtin_amdgcn_mfma_f32_16x16x32_bf16(a1, bfr[1], acc, 0, 0, 0);

    if (tile == 0) {
        u16x4 ov;
        if (g < 2) {
#pragma unroll
            for (int r = 0; r < 4; ++r) ov[r] = bf_hi((acc[r] + bq[g * 4 + r]) * 0.125f);
            *(u16x4*)&Qb[(b * 4096 + n) * 8 + g * 4] = ov;
        } else {
#pragma unroll
            for (int r = 0; r < 4; ++r) ov[r] = bf_hi(acc[r] + bk[(g - 2) * 4 + r]);
            *(u16x4*)&Kb[(b * 4096 + n) * 8 + (g - 2) * 4] = ov;
        }
        // fused avg partials (tile-0 blocks only): re-read own x tile (L2-hot)
        const int c = tid >> 2;
        const float* xrow = xb + c * 4096 + n0 + ((tid & 3) << 4);
        float s = 0.0f;
#pragma unroll
        for (int k = 0; k < 4; ++k) {
            const float4 v = *(const float4*)&xrow[k * 4];
            s += (v.x + v.y) + (v.z + v.w);
        }
        s += __shfl_xor(s, 1);
        s += __shfl_xor(s, 2);
        if ((tid & 3) == 0) atomicAdd(&avg[b * 64 + c], s * (1.0f / 4096.0f));
    } else {
#pragma unroll
        for (int r = 0; r < 4; ++r) {
            const int v = (tile - 1) * 16 + g * 4 + r;
            Vb[(b * 64 + v) * 4096 + n] = bf_hi(acc[r] + bv[v]);
        }
    }
}

// ---------------------------------------------------------------------------
// Kernel B: attention + gate. grid = 512 (XCD-chunk-swizzled), 256 thr/4 waves.
// Block = (b, 32-query tile). ONE barrier per 64-m tile:
//   A: ds_write V(i) from prefetch regs; QK(i) MFMA -> exp -> Ps[i&1];
//      issue global loads for tile i+1            (T14: full-iter latency hide)
//   bar
//   B: PV(i) via 4 MFMA from Vs[i&1], Ps[i&1]     (T5: setprio around cluster)
// Double-buffered Vs AND Ps: A(i+2)'s overwrite of buffer i&1 is separated
// from B(i) by bar(i+1) -> race-free with a single barrier per tile.
// ---------------------------------------------------------------------------
__global__ __launch_bounds__(256) void attn_kernel(
    const unsigned short* __restrict__ Qb, const unsigned short* __restrict__ Kb,
    const unsigned short* __restrict__ Vb, const float* __restrict__ avg,
    const float* __restrict__ W1, const float* __restrict__ b1,
    const float* __restrict__ W2, const float* __restrict__ b2,
    float* __restrict__ out)
{
    __shared__ __align__(16) unsigned short Vs[2][64][64];
    __shared__ __align__(16) unsigned short Ps[2][32][64];
    __shared__ float zls[32], gls[64], avgs[64];

    const int t = threadIdx.x;
    const int w = t >> 6;
    const int l = t & 63;
    const int g = l >> 4;
    const int l15 = l & 15;

    // bijective XCD chunk swizzle (512 % 8 == 0)
    const int wg = (blockIdx.x & 7) * 64 + (blockIdx.x >> 3);
    const int b = wg >> 7;
    const int q0 = (wg & 127) << 5;

    if (t < 32) zls[t] = 0.0f;
    if (t < 64) avgs[t] = avg[b * 64 + t];

    // Q fragments (B operand): col=q, k-group 0 = 8 channels, groups 1-3 zero
    bf16x8 zf = {};
    bf16x8 qf[2];
#pragma unroll
    for (int qt = 0; qt < 2; ++qt) {
        bf16x8 v = *(const bf16x8*)&Qb[(b * 4096 + q0 + qt * 16 + l15) * 8];
        qf[qt] = (g == 0) ? v : zf;
    }

    // V staging geometry: 256 threads stage 64x64 bf16; XOR-swizzled rows
    const int srow = t >> 2;
    const int scol = (t & 3) << 4;
    const int ssw = (srow & 7) << 3;
    const unsigned short* vsrc = &Vb[(b * 64 + srow) * 4096];
    const int mrow = w * 16 + l15;

    // prologue: prefetch tile 0 into regs
    u16x8 va = *(const u16x8*)&vsrc[scol];
    u16x8 vb2 = *(const u16x8*)&vsrc[scol + 8];
    bf16x8 kreg;
    {
        bf16x8 kv = *(const bf16x8*)&Kb[(b * 4096 + mrow) * 8];
        kreg = (g == 0) ? kv : zf;
    }

    f32x4 acc[2];
#pragma unroll
    for (int qt = 0; qt < 2; ++qt)
#pragma unroll
        for (int r = 0; r < 4; ++r) acc[qt][r] = 0.0f;
    float zreg[2] = {0.f, 0.f};
    const int vsw = (l15 & 7) << 3;
    const int psw = (l15 & 7) << 3;

    __syncthreads();   // zls/avgs init visible (also aligns waves at loop entry)

    for (int i = 0; i < 64; ++i) {
        const int buf = i & 1;

        // ---- phase A ----
        // ds_write V(i) from prefetch regs (reads regs at issue; safe vs reload)
        {
            unsigned short* dst = &Vs[buf][srow][0];
            *(u16x8*)&dst[scol ^ ssw] = va;
            *(u16x8*)&dst[(scol + 8) ^ ssw] = vb2;
        }
        const bf16x8 kf = kreg;   // tile i K-frag

        // issue tile i+1 global loads (consumed in A(i+1))
        const int inx = (i < 63) ? i + 1 : 63;
        va  = *(const u16x8*)&vsrc[inx * 64 + scol];
        vb2 = *(const u16x8*)&vsrc[inx * 64 + scol + 8];
        {
            bf16x8 kv = *(const bf16x8*)&Kb[(b * 4096 + inx * 64 + mrow) * 8];
            kreg = (g == 0) ? kv : zf;
        }

        // QK -> exp -> Ps[buf]
        f32x4 dz;
#pragma unroll
        for (int r = 0; r < 4; ++r) dz[r] = 0.0f;
#pragma unroll
        for (int qt = 0; qt < 2; ++qt) {
            f32x4 d = __builtin_amdgcn_mfma_f32_16x16x32_bf16(kf, qf[qt], dz, 0, 0, 0);
            float p[4];
#pragma unroll
            for (int r = 0; r < 4; ++r) p[r] = __expf(d[r]);
            zreg[qt] += (p[0] + p[1]) + (p[2] + p[3]);
            u16x4 pw;
#pragma unroll
            for (int r = 0; r < 4; ++r) pw[r] = bf_hi(p[r]);
            const int q = qt * 16 + l15;
            *(u16x4*)&Ps[buf][q][(w * 16 + g * 4) ^ ((q & 7) << 3)] = pw;
        }

        __syncthreads();   // the ONE barrier: Vs[buf]/Ps[buf] visible to all

        // ---- phase B: PV ----
        {
            const unsigned short* vbuf = &Vs[buf][w * 16 + l15][0];
            __builtin_amdgcn_s_setprio(1);
#pragma unroll
            for (int kcb = 0; kcb < 2; ++kcb) {
                const int colA = kcb * 32 + g * 8;
                const bf16x8 af = *(const bf16x8*)&vbuf[colA ^ vsw];
#pragma unroll
                for (int qt = 0; qt < 2; ++qt) {
                    const bf16x8 bfr = *(const bf16x8*)&Ps[buf][qt * 16 + l15][colA ^ psw];
                    acc[qt] = __builtin_amdgcn_mfma_f32_16x16x32_bf16(af, bfr, acc[qt], 0, 0, 0);
                }
            }
            __builtin_amdgcn_s_setprio(0);
        }
    }

    // z reduction: shfl over g-groups, then LDS atomic across waves
#pragma unroll
    for (int qt = 0; qt < 2; ++qt) {
        float z = zreg[qt];
        z += __shfl_xor(z, 16);
        z += __shfl_xor(z, 32);
        if (g == 0) atomicAdd(&zls[qt * 16 + l15], z);
    }
    // SE gate (redundant per block, tiny)
    if (t < 64) {
        float hreg[4];
#pragma unroll
        for (int j = 0; j < 4; ++j) {
            float hh = b1[j];
            for (int c = 0; c < 64; ++c) hh += W1[j * 64 + c] * avgs[c];
            hreg[j] = fmaxf(hh, 0.0f);
        }
        float gg = b2[t];
#pragma unroll
        for (int j = 0; j < 4; ++j) gg += W2[t * 4 + j] * hreg[j];
        gls[t] = 1.0f / (1.0f + __expf(-gg));
    }
    __syncthreads();

#pragma unroll
    for (int qt = 0; qt < 2; ++qt) {
        const int q = qt * 16 + l15;
        const float rz = 1.0f / zls[q];
#pragma unroll
        for (int r = 0; r < 4; ++r) {
            const int v = w * 16 + g * 4 + r;
            out[(b * 64 + v) * 4096 + q0 + q] = acc[qt][r] * rz * gls[v];
        }
    }
}

extern "C" void kernel_launch(void* const* d_in, const int* in_sizes, int n_in,
                              void* d_out, int out_size, void* d_ws, size_t ws_size,
                              hipStream_t stream) {
    const float* x  = (const float*)d_in[0];
    const float* Wq = (const float*)d_in[1];
    const float* bq = (const float*)d_in[2];
    const float* Wk = (const float*)d_in[3];
    const float* bk = (const float*)d_in[4];
    const float* Wv = (const float*)d_in[5];
    const float* bv = (const float*)d_in[6];
    const float* W1 = (const float*)d_in[7];
    const float* b1 = (const float*)d_in[8];
    const float* W2 = (const float*)d_in[9];
    const float* b2 = (const float*)d_in[10];

    unsigned short* wsu = (unsigned short*)d_ws;
    unsigned short* Qb = wsu + WS_QB;
    unsigned short* Kb = wsu + WS_KB;
    unsigned short* Vb = wsu + WS_VB;
    float* avg = (float*)(wsu + WS_AVG_U);
    float* out = (float*)d_out;

    hipMemsetAsync(avg, 0, 256 * sizeof(float), stream);
    proj_kernel<<<1280, 256, 0, stream>>>(x, Wq, bq, Wk, bk, Wv, bv, Qb, Kb, Vb, avg);
    attn_kernel<<<512, 256, 0, stream>>>(Qb, Kb, Vb, avg, W1, b1, W2, b2, out);
}